// Round 15
// baseline (39.101 us; speedup 1.0000x reference)
//
#include <hip/hip_runtime.h>
#include <math.h>

// ---- A: 4-plane masks + zero deg/done + CE (block 0) -> out[0] ------------
__global__ __launch_bounds__(256) void kA_mask_zero_ce(
        const int* __restrict__ row, const int* __restrict__ col,
        const int* __restrict__ batch,
        unsigned int* __restrict__ deg, unsigned int* __restrict__ done,
        unsigned long long* __restrict__ mask,
        int E, int T4, int nW, int N,
        const float* __restrict__ logits, const int* __restrict__ labels,
        float* __restrict__ out, int G, int C) {
    int t = blockIdx.x * blockDim.x + threadIdx.x;
    int nth = gridDim.x * blockDim.x;
    int lane = threadIdx.x & 63;
    int w = t >> 6;

    // zero deg (vectorized) + done
    int N4 = N >> 2;
    for (int i = t; i < N4; i += nth) ((uint4*)deg)[i] = make_uint4(0u, 0u, 0u, 0u);
    for (int i = (N4 << 2) + t; i < N; i += nth) deg[i] = 0u;
    if (t == 0) *done = 0u;

    // masks: 4 edges/thread via int4
    int4 r4 = make_int4(0, 0, 0, 0), c4 = make_int4(0, 0, 0, 0);
    if (t < T4) {
        r4 = ((const int4*)row)[t];
        c4 = ((const int4*)col)[t];
    }
    int rr[4] = { r4.x, r4.y, r4.z, r4.w };
    int cc[4] = { c4.x, c4.y, c4.z, c4.w };
    bool h[4];
    #pragma unroll
    for (int j = 0; j < 4; ++j) {
        int e = (t << 2) + j;
        h[j] = (t < T4) && (e < E) && (batch[rr[j]] == batch[cc[j]]);
    }
    #pragma unroll
    for (int j = 0; j < 4; ++j) {
        unsigned long long b = __ballot(h[j]);
        if (lane == 0 && w < nW) mask[(w << 2) + j] = b;
    }

    // CE on block 0; writes ce into out[0]; B adds energy.
    if (blockIdx.x == 0) {
        __shared__ float sh[128];
        int g = threadIdx.x;
        if (g < 128) {
            float lp = 0.f;
            if (g < G) {
                const float* lg = logits + (size_t)g * C;
                float mx = lg[0];
                for (int d = 1; d < C; ++d) mx = fmaxf(mx, lg[d]);
                float s = 0.f;
                for (int d = 0; d < C; ++d) s += expf(lg[d] - mx);
                lp = lg[labels[g]] - mx - logf(s);
            }
            sh[g] = lp;
        }
        __syncthreads();
        for (int o = 64; o > 0; o >>= 1) {
            if (threadIdx.x < o) sh[threadIdx.x] += sh[threadIdx.x + o];
            __syncthreads();
        }
        if (threadIdx.x == 0) out[0] = (float)(-(double)sh[0] / (double)G);
    }
}

// ---- B: deg atomics -> spin grid barrier -> energy ------------------------
// 256 blocks x 256 threads: fully co-resident on 256 CUs -> spin is safe.
__global__ __launch_bounds__(256) void kB_deg_energy(
        const float* __restrict__ x,
        const int* __restrict__ row, const int* __restrict__ col,
        unsigned int* __restrict__ deg, unsigned int* __restrict__ done,
        const unsigned long long* __restrict__ mask,
        const int* __restrict__ batch,
        float* __restrict__ out, int nWordsTot, int wpb, int D4, int N,
        int nGrid) {
    const int lane = threadIdx.x & 63;
    const int wv = threadIdx.x >> 6;
    int w0 = blockIdx.x * wpb;
    int w1 = (w0 + wpb < nWordsTot) ? (w0 + wpb) : nWordsTot;

    // phase 1: deg atomics for own words (lane l handles bit l)
    for (int W = w0 + wv; W < w1; W += 4) {
        unsigned long long m = mask[W];
        if ((m >> lane) & 1ULL) {
            int e = ((((W >> 2) << 6) + lane) << 2) + (W & 3);
            atomicAdd(&deg[row[e]], 1u);
        }
    }

    // grid barrier: ticket + spin (all blocks resident)
    __syncthreads();                      // drains this block's atomics (vmcnt)
    if (threadIdx.x == 0) {
        __threadfence();
        atomicAdd(done, 1u);
        while (__hip_atomic_load(done, __ATOMIC_ACQUIRE,
                                 __HIP_MEMORY_SCOPE_AGENT) < (unsigned)nGrid) {
            __builtin_amdgcn_s_sleep(2);
        }
    }
    __syncthreads();

    // phase 3: energy over own words
    double wsum = 0.0;
    for (int W = w0 + wv; W < w1; W += 4) {
        unsigned long long m = mask[W];
        while (m) {
            int b = __ffsll(m) - 1;
            m &= m - 1;
            int e = ((((W >> 2) << 6) + b) << 2) + (W & 3);
            int r = row[e], c = col[e];           // uniform broadcast loads
            unsigned int dr = 0u, dc = 0u;
            if (lane == 0) {
                dr = __hip_atomic_load(&deg[r], __ATOMIC_RELAXED,
                                       __HIP_MEMORY_SCOPE_AGENT);
                dc = __hip_atomic_load(&deg[c], __ATOMIC_RELAXED,
                                       __HIP_MEMORY_SCOPE_AGENT);
            }
            dr = __shfl(dr, 0);
            dc = __shfl(dc, 0);
            if (dc == 0u) continue;               // dr >= 1 by construction
            const float4 a = ((const float4*)(x + (size_t)r * (size_t)(D4 * 4)))[lane];
            const float4 bb = ((const float4*)(x + (size_t)c * (size_t)(D4 * 4)))[lane];
            float dx = a.x - bb.x, dy = a.y - bb.y, dz = a.z - bb.z, dw = a.w - bb.w;
            float ss = dx * dx + dy * dy + dz * dz + dw * dw;
            #pragma unroll
            for (int o = 32; o > 0; o >>= 1) ss += __shfl_xor(ss, o);
            if (lane == 0) {
                float ir = 1.0f / sqrtf((float)dr);
                float ic = 1.0f / sqrtf((float)dc);
                wsum += (double)((ir * ic) * ss);
            }
        }
    }

    // block reduce 4 wave sums -> 1 f32 atomic
    __shared__ double sdw[4];
    if (lane == 0) sdw[wv] = wsum;
    __syncthreads();
    if (threadIdx.x == 0) {
        double bsum = sdw[0] + sdw[1] + sdw[2] + sdw[3];
        if (bsum != 0.0) {
            double ng = (double)(batch[N - 1] + 1);
            atomicAdd(out, (float)(bsum / ng));
        }
    }
}

extern "C" void kernel_launch(void* const* d_in, const int* in_sizes, int n_in,
                              void* d_out, int out_size, void* d_ws, size_t ws_size,
                              hipStream_t stream) {
    const float* logits = (const float*)d_in[0];
    const int* labels = (const int*)d_in[1];
    const float* x = (const float*)d_in[2];
    const int* edge_index = (const int*)d_in[3];
    const int* batch = (const int*)d_in[4];

    const int C = 10;
    const int G = in_sizes[0] / C;            // 128
    const int E = in_sizes[3] / 2;            // 320000
    const int N = in_sizes[4];                // 100000
    const int D = in_sizes[2] / N;            // 256
    const int D4 = D / 4;

    const int* row = edge_index;
    const int* col = edge_index + E;

    int T4 = (E + 3) / 4;                     // 80000
    int nW = (T4 + 63) / 64;                  // 1250
    int nWordsTot = nW * 4;                   // 5000

    // workspace: deg[N] | done | pad | mask[nWordsTot]
    size_t off = 0;
    unsigned int* deg = (unsigned int*)((char*)d_ws + off); off += (size_t)N * 4;
    unsigned int* done = (unsigned int*)((char*)d_ws + off); off += 16;
    unsigned long long* mask = (unsigned long long*)((char*)d_ws + off);

    float* out = (float*)d_out;

    int aBlocks = (T4 + 255) / 256;           // 313
    kA_mask_zero_ce<<<aBlocks, 256, 0, stream>>>(
        row, col, batch, deg, done, mask, E, T4, nW, N,
        logits, labels, out, G, C);

    int bGrid = 256;                          // co-resident: 1 block/CU
    int wpb = (nWordsTot + bGrid - 1) / bGrid;  // 20
    kB_deg_energy<<<bGrid, 256, 0, stream>>>(
        x, row, col, deg, done, mask, batch, out, nWordsTot, wpb, D4, N, bGrid);
}

// Round 16
// 19.932 us; speedup vs baseline: 1.9617x; 1.9617x over previous
//
#include <hip/hip_runtime.h>
#include <math.h>

// ---- K0: zero packed-deg, build batch8, CE (block 0) -> out[0] ------------
__global__ __launch_bounds__(256) void k0_init_ce(
        unsigned int* __restrict__ degP, unsigned char* __restrict__ batch8,
        const int* __restrict__ batch, int N, int nDegW,
        const float* __restrict__ logits, const int* __restrict__ labels,
        float* __restrict__ out, int G, int C) {
    int tid = blockIdx.x * blockDim.x + threadIdx.x;
    int nthreads = gridDim.x * blockDim.x;

    // zero packed deg: nDegW words (100 KB), vectorized
    int nDegW4 = nDegW >> 2;
    for (int i = tid; i < nDegW4; i += nthreads)
        ((uint4*)degP)[i] = make_uint4(0u, 0u, 0u, 0u);
    for (int i = (nDegW4 << 2) + tid; i < nDegW; i += nthreads) degP[i] = 0u;

    // batch8: int -> byte (values < 128)
    int N4 = N >> 2;
    for (int i = tid; i < N4; i += nthreads) {
        int4 b4 = ((const int4*)batch)[i];
        uchar4 p;
        p.x = (unsigned char)b4.x; p.y = (unsigned char)b4.y;
        p.z = (unsigned char)b4.z; p.w = (unsigned char)b4.w;
        ((uchar4*)batch8)[i] = p;
    }
    for (int i = (N4 << 2) + tid; i < N; i += nthreads)
        batch8[i] = (unsigned char)batch[i];

    if (blockIdx.x == 0) {
        __shared__ float sh[128];
        int g = threadIdx.x;
        if (g < 128) {
            float lp = 0.f;
            if (g < G) {
                const float* lg = logits + (size_t)g * C;
                float mx = lg[0];
                for (int d = 1; d < C; ++d) mx = fmaxf(mx, lg[d]);
                float s = 0.f;
                for (int d = 0; d < C; ++d) s += expf(lg[d] - mx);
                lp = lg[labels[g]] - mx - logf(s);
            }
            sh[g] = lp;
        }
        __syncthreads();
        for (int o = 64; o > 0; o >>= 1) {
            if (threadIdx.x < o) sh[threadIdx.x] += sh[threadIdx.x + o];
            __syncthreads();
        }
        if (threadIdx.x == 0) out[0] = (float)(-(double)sh[0] / (double)G);
    }
}

// ---- K1: 4 edges/thread; packed-byte deg atomics + 4-plane ballot masks ---
__global__ __launch_bounds__(256) void k1_deg_mask(
        const int* __restrict__ row, const int* __restrict__ col,
        const unsigned char* __restrict__ batch8,
        unsigned int* __restrict__ degP,
        unsigned long long* __restrict__ mask, int E, int T4, int nW) {
    int t = blockIdx.x * blockDim.x + threadIdx.x;
    int lane = threadIdx.x & 63;
    int w = t >> 6;

    int4 r4 = make_int4(0, 0, 0, 0), c4 = make_int4(0, 0, 0, 0);
    if (t < T4) {
        r4 = ((const int4*)row)[t];
        c4 = ((const int4*)col)[t];
    }
    int rr[4] = { r4.x, r4.y, r4.z, r4.w };
    int cc[4] = { c4.x, c4.y, c4.z, c4.w };

    bool h[4];
    #pragma unroll
    for (int j = 0; j < 4; ++j) {
        int e = (t << 2) + j;
        h[j] = (t < T4) && (e < E) && (batch8[rr[j]] == batch8[cc[j]]);
        if (h[j]) atomicAdd(&degP[rr[j] >> 2], 1u << ((rr[j] & 3) * 8));
    }
    #pragma unroll
    for (int j = 0; j < 4; ++j) {
        unsigned long long b = __ballot(h[j]);
        if (lane == 0 && w < nW) mask[(w << 2) + j] = b;
    }
}

// ---- K2: energy; 4-plane mask-predicated; byte-deg; adds into out[0] ------
__global__ __launch_bounds__(256) void k2_energy(
        const float* __restrict__ x,
        const int* __restrict__ row, const int* __restrict__ col,
        const unsigned int* __restrict__ degP,
        const unsigned long long* __restrict__ mask,
        const int* __restrict__ batch,
        float* __restrict__ out, int D4, int N, int nW) {
    int gtid = blockIdx.x * blockDim.x + threadIdx.x;
    int wave = gtid >> 6;
    int lane = threadIdx.x & 63;
    int wv = threadIdx.x >> 6;

    double wsum = 0.0;
    if (wave < nW) {
        unsigned long long m0 = mask[(wave << 2) + 0];
        unsigned long long m1 = mask[(wave << 2) + 1];
        unsigned long long m2 = mask[(wave << 2) + 2];
        unsigned long long m3 = mask[(wave << 2) + 3];
        unsigned long long planes[4] = { m0, m1, m2, m3 };
        if (m0 | m1 | m2 | m3) {
            #pragma unroll
            for (int j = 0; j < 4; ++j) {
                unsigned long long m = planes[j];
                if (!m) continue;
                int e = (((wave << 6) + lane) << 2) + j;
                bool bit = (m >> lane) & 1ULL;
                int r = 0, c = 0;
                float norm = 0.f;
                bool hit = false;
                if (bit) {
                    r = row[e];
                    c = col[e];
                    unsigned int wr = degP[r >> 2];
                    unsigned int wc = degP[c >> 2];
                    unsigned int dr = (wr >> ((r & 3) * 8)) & 0xffu;  // >= 1
                    unsigned int dc = (wc >> ((c & 3) * 8)) & 0xffu;
                    if (dc > 0u) {
                        norm = 1.0f / sqrtf((float)(dr * dc));
                        hit = true;
                    }
                }
                unsigned long long bm = __ballot(hit);
                while (bm) {
                    int src = __ffsll((unsigned long long)bm) - 1;
                    bm &= bm - 1;
                    int rs = __shfl(r, src);
                    int cs = __shfl(c, src);
                    float nn = __shfl(norm, src);
                    const float4 a = ((const float4*)(x + (size_t)rs * (size_t)(D4 * 4)))[lane];
                    const float4 b = ((const float4*)(x + (size_t)cs * (size_t)(D4 * 4)))[lane];
                    float dx = a.x - b.x, dy = a.y - b.y, dz = a.z - b.z, dw = a.w - b.w;
                    float ss = dx * dx + dy * dy + dz * dz + dw * dw;
                    #pragma unroll
                    for (int o = 32; o > 0; o >>= 1) ss += __shfl_xor(ss, o);
                    if (lane == 0) wsum += (double)(nn * ss);
                }
            }
        }
    }

    __shared__ double sdw[4];
    if (lane == 0) sdw[wv] = wsum;
    __syncthreads();
    if (threadIdx.x == 0) {
        double bsum = sdw[0] + sdw[1] + sdw[2] + sdw[3];
        if (bsum != 0.0) {
            double ng = (double)(batch[N - 1] + 1);
            atomicAdd(out, (float)(bsum / ng));
        }
    }
}

extern "C" void kernel_launch(void* const* d_in, const int* in_sizes, int n_in,
                              void* d_out, int out_size, void* d_ws, size_t ws_size,
                              hipStream_t stream) {
    const float* logits = (const float*)d_in[0];
    const int* labels = (const int*)d_in[1];
    const float* x = (const float*)d_in[2];
    const int* edge_index = (const int*)d_in[3];
    const int* batch = (const int*)d_in[4];

    const int C = 10;
    const int G = in_sizes[0] / C;            // 128
    const int E = in_sizes[3] / 2;            // 320000
    const int N = in_sizes[4];                // 100000
    const int D = in_sizes[2] / N;            // 256
    const int D4 = D / 4;

    const int* row = edge_index;
    const int* col = edge_index + E;

    int T4 = (E + 3) / 4;                     // 80000 threads in K1
    int nW = (T4 + 63) / 64;                  // 1250 wave-groups (4 planes each)
    int nDegW = (N + 3) / 4;                  // 25000 packed words (100 KB)

    // workspace: degP[nDegW] | batch8[N] | pad | mask[4*nW]
    size_t off = 0;
    unsigned int* degP = (unsigned int*)((char*)d_ws + off); off += (size_t)nDegW * 4;
    unsigned char* batch8 = (unsigned char*)((char*)d_ws + off); off += (size_t)N;
    off = (off + 15) & ~(size_t)15;
    unsigned long long* mask = (unsigned long long*)((char*)d_ws + off);

    float* out = (float*)d_out;

    k0_init_ce<<<128, 256, 0, stream>>>(degP, batch8, batch, N, nDegW,
                                        logits, labels, out, G, C);

    int k1Blocks = (T4 + 255) / 256;          // 313
    k1_deg_mask<<<k1Blocks, 256, 0, stream>>>(row, col, batch8, degP,
                                              mask, E, T4, nW);

    int k2Blocks = (nW + 3) / 4;              // 313
    k2_energy<<<k2Blocks, 256, 0, stream>>>(x, row, col, degP, mask, batch,
                                            out, D4, N, nW);
}

// Round 17
// 19.649 us; speedup vs baseline: 1.9900x; 1.0144x over previous
//
#include <hip/hip_runtime.h>
#include <math.h>

// ---- K0: zero deg, build batch8, CE (block 0) -> out[0] -------------------
__global__ __launch_bounds__(256) void k0_init_ce(
        unsigned int* __restrict__ deg, unsigned char* __restrict__ batch8,
        const int* __restrict__ batch, int N,
        const float* __restrict__ logits, const int* __restrict__ labels,
        float* __restrict__ out, int G, int C) {
    int tid = blockIdx.x * blockDim.x + threadIdx.x;
    int nthreads = gridDim.x * blockDim.x;
    int N4 = N >> 2;  // N % 4 == 0 here; tail handled below
    for (int i = tid; i < N4; i += nthreads) {
        ((uint4*)deg)[i] = make_uint4(0u, 0u, 0u, 0u);
        int4 b4 = ((const int4*)batch)[i];
        uchar4 p;
        p.x = (unsigned char)b4.x; p.y = (unsigned char)b4.y;
        p.z = (unsigned char)b4.z; p.w = (unsigned char)b4.w;
        ((uchar4*)batch8)[i] = p;
    }
    for (int i = (N4 << 2) + tid; i < N; i += nthreads) {  // tail
        deg[i] = 0u;
        batch8[i] = (unsigned char)batch[i];
    }

    if (blockIdx.x == 0) {
        __shared__ float sh[128];
        int g = threadIdx.x;
        if (g < 128) {
            float lp = 0.f;
            if (g < G) {
                const float* lg = logits + (size_t)g * C;
                float mx = lg[0];
                for (int d = 1; d < C; ++d) mx = fmaxf(mx, lg[d]);
                float s = 0.f;
                for (int d = 0; d < C; ++d) s += expf(lg[d] - mx);
                lp = lg[labels[g]] - mx - logf(s);
            }
            sh[g] = lp;
        }
        __syncthreads();
        for (int o = 64; o > 0; o >>= 1) {
            if (threadIdx.x < o) sh[threadIdx.x] += sh[threadIdx.x + o];
            __syncthreads();
        }
        if (threadIdx.x == 0) out[0] = (float)(-(double)sh[0] / (double)G);
    }
}

// ---- K1: 4 edges/thread; deg atomics + 4-plane ballot masks ---------------
__global__ __launch_bounds__(256) void k1_deg_mask(
        const int* __restrict__ row, const int* __restrict__ col,
        const unsigned char* __restrict__ batch8,
        unsigned int* __restrict__ deg,
        unsigned long long* __restrict__ mask, int E, int T4, int nW) {
    int t = blockIdx.x * blockDim.x + threadIdx.x;
    int lane = threadIdx.x & 63;
    int w = t >> 6;

    int4 r4 = make_int4(0, 0, 0, 0), c4 = make_int4(0, 0, 0, 0);
    if (t < T4) {
        r4 = ((const int4*)row)[t];
        c4 = ((const int4*)col)[t];
    }
    int rr[4] = { r4.x, r4.y, r4.z, r4.w };
    int cc[4] = { c4.x, c4.y, c4.z, c4.w };

    bool h[4];
    #pragma unroll
    for (int j = 0; j < 4; ++j) {
        int e = (t << 2) + j;
        h[j] = (t < T4) && (e < E) && (batch8[rr[j]] == batch8[cc[j]]);
        if (h[j]) atomicAdd(&deg[rr[j]], 1u);
    }
    #pragma unroll
    for (int j = 0; j < 4; ++j) {
        unsigned long long b = __ballot(h[j]);
        if (lane == 0 && w < nW) mask[(w << 2) + j] = b;
    }
}

// ---- K2: energy; 4-plane mask-predicated; adds into out[0] ----------------
__global__ __launch_bounds__(256) void k2_energy(
        const float* __restrict__ x,
        const int* __restrict__ row, const int* __restrict__ col,
        const unsigned int* __restrict__ deg,
        const unsigned long long* __restrict__ mask,
        const int* __restrict__ batch,
        float* __restrict__ out, int D4, int N, int nW) {
    int gtid = blockIdx.x * blockDim.x + threadIdx.x;
    int wave = gtid >> 6;
    int lane = threadIdx.x & 63;
    int wv = threadIdx.x >> 6;

    double wsum = 0.0;
    if (wave < nW) {
        unsigned long long m0 = mask[(wave << 2) + 0];
        unsigned long long m1 = mask[(wave << 2) + 1];
        unsigned long long m2 = mask[(wave << 2) + 2];
        unsigned long long m3 = mask[(wave << 2) + 3];
        unsigned long long planes[4] = { m0, m1, m2, m3 };
        if (m0 | m1 | m2 | m3) {
            #pragma unroll
            for (int j = 0; j < 4; ++j) {
                unsigned long long m = planes[j];
                if (!m) continue;
                int e = (((wave << 6) + lane) << 2) + j;
                bool bit = (m >> lane) & 1ULL;
                int r = 0, c = 0;
                float norm = 0.f;
                bool hit = false;
                if (bit) {
                    r = row[e];
                    c = col[e];
                    unsigned int dr = deg[r];   // >= 1 (this edge counted)
                    unsigned int dc = deg[c];
                    if (dc > 0u) {
                        float ir = 1.0f / sqrtf((float)dr);
                        float ic = 1.0f / sqrtf((float)dc);
                        norm = ir * ic;
                        hit = true;
                    }
                }
                unsigned long long bm = __ballot(hit);
                while (bm) {
                    int src = __ffsll((unsigned long long)bm) - 1;
                    bm &= bm - 1;
                    int rs = __shfl(r, src);
                    int cs = __shfl(c, src);
                    float nn = __shfl(norm, src);
                    const float4 a = ((const float4*)(x + (size_t)rs * (size_t)(D4 * 4)))[lane];
                    const float4 b = ((const float4*)(x + (size_t)cs * (size_t)(D4 * 4)))[lane];
                    float dx = a.x - b.x, dy = a.y - b.y, dz = a.z - b.z, dw = a.w - b.w;
                    float ss = dx * dx + dy * dy + dz * dz + dw * dw;
                    #pragma unroll
                    for (int o = 32; o > 0; o >>= 1) ss += __shfl_xor(ss, o);
                    if (lane == 0) wsum += (double)(nn * ss);
                }
            }
        }
    }

    __shared__ double sdw[4];
    if (lane == 0) sdw[wv] = wsum;
    __syncthreads();
    if (threadIdx.x == 0) {
        double bsum = sdw[0] + sdw[1] + sdw[2] + sdw[3];
        if (bsum != 0.0) {
            double ng = (double)(batch[N - 1] + 1);
            atomicAdd(out, (float)(bsum / ng));
        }
    }
}

extern "C" void kernel_launch(void* const* d_in, const int* in_sizes, int n_in,
                              void* d_out, int out_size, void* d_ws, size_t ws_size,
                              hipStream_t stream) {
    const float* logits = (const float*)d_in[0];
    const int* labels = (const int*)d_in[1];
    const float* x = (const float*)d_in[2];
    const int* edge_index = (const int*)d_in[3];
    const int* batch = (const int*)d_in[4];

    const int C = 10;
    const int G = in_sizes[0] / C;            // 128
    const int E = in_sizes[3] / 2;            // 320000
    const int N = in_sizes[4];                // 100000
    const int D = in_sizes[2] / N;            // 256
    const int D4 = D / 4;

    const int* row = edge_index;
    const int* col = edge_index + E;

    int T4 = (E + 3) / 4;                     // 80000 threads in K1
    int nW = (T4 + 63) / 64;                  // 1250 wave-groups (4 planes each)

    // workspace: deg[N] | batch8[N] | pad | mask[4*nW]
    size_t off = 0;
    unsigned int* deg = (unsigned int*)((char*)d_ws + off); off += (size_t)N * 4;
    unsigned char* batch8 = (unsigned char*)((char*)d_ws + off); off += (size_t)N;
    off = (off + 15) & ~(size_t)15;
    unsigned long long* mask = (unsigned long long*)((char*)d_ws + off);

    float* out = (float*)d_out;

    k0_init_ce<<<128, 256, 0, stream>>>(deg, batch8, batch, N,
                                        logits, labels, out, G, C);

    int k1Blocks = (T4 + 255) / 256;          // 313
    k1_deg_mask<<<k1Blocks, 256, 0, stream>>>(row, col, batch8, deg,
                                              mask, E, T4, nW);

    int k2Blocks = (nW + 3) / 4;              // 313
    k2_energy<<<k2Blocks, 256, 0, stream>>>(x, row, col, deg, mask, batch,
                                            out, D4, N, nW);
}